// Round 5
// baseline (84.619 us; speedup 1.0000x reference)
//
#include <hip/hip_runtime.h>
#include <math.h>

#define NB   4
#define CIN  512
#define HID  64
#define NK   11     // NUM_CLASSES+1
#define H1   60
#define W1p  80
#define P1   4800
#define H2   30
#define W2p  40
#define P2   1200
#define HO   480
#define WOp  640
#define NP1  (NB*P1)    // 19200
#define NP2  (NB*P2)    // 4800
#define PLANE ((size_t)HO*WOp)                  // 307200
#define SEG_OFF ((size_t)NB*NK*PLANE)           // 13,516,800
#define BBX_OFF (SEG_OFF + (size_t)NB*PLANE)    // 14,745,600

// partial-sum scratch inside d_out's probability region (overwritten by
// upsample_kernel at the end): f1 partials 4*19200*64, f2 partials 4*4800*64
#define F1P_OFF 0
#define F2P_OFF ((size_t)4 * NP1 * 64)          // 4,915,200 (< 13.5M region)

// ws layout in floats
#define WS_WT1 0
#define WS_WT2 32768
#define WS_PRB 65536                            // 19200*12 = 230,400
#define WS_SEG (WS_PRB + NP1*12)                // 19200 ints

// ---------------- transpose weights: wT[c*64+o] = w[o*512+c] ----------------
__global__ __launch_bounds__(256) void transpose_w(const float* __restrict__ w1,
                                                   const float* __restrict__ w2,
                                                   float* __restrict__ ws) {
    int i = blockIdx.x * 256 + threadIdx.x;   // 0..32767
    if (i >= HID * CIN) return;
    int o = i >> 9;           // /512
    int c = i & 511;
    ws[WS_WT1 + c * HID + o] = w1[i];
    ws[WS_WT2 + c * HID + o] = w2[i];
}

// ---------------- conv partials: block = (64-px tile) x (128-ch group) ------
// 1504 blocks x 256 thr (4 waves). Wave rg: rows 16rg..16rg+15, lane = pixel.
// acc[16], 8-deep double-buffered x prefetch, no LDS -> ~6 blocks/CU resident,
// HBM latency hidden by TLP. Raw partial sums (no bias/relu) -> d_out scratch.
__global__ __launch_bounds__(256) void conv_part(const float* __restrict__ f1,
                                                 const float* __restrict__ f2,
                                                 const float* __restrict__ wt1,
                                                 const float* __restrict__ wt2,
                                                 float* __restrict__ outp) {
    int t = blockIdx.x;
    const float* X; const float* wT; float* Pout;
    int P, px0, cg;
    if (t < 1200) {
        int tile = t >> 2; cg = t & 3;
        int b = tile / 75; px0 = (tile % 75) * 64;
        X  = f1 + (size_t)b * CIN * P1;  P = P1;
        wT = wt1;
        Pout = outp + F1P_OFF + ((size_t)cg * NP1 + (size_t)b * P1) * 64;
    } else {
        int u = t - 1200; int tile = u >> 2; cg = u & 3;
        int b = tile / 19; px0 = (tile % 19) * 64;
        X  = f2 + (size_t)b * CIN * P2;  P = P2;
        wT = wt2;
        Pout = outp + F2P_OFF + ((size_t)cg * NP2 + (size_t)b * P2) * 64;
    }
    int lane  = threadIdx.x & 63;
    int wv    = threadIdx.x >> 6;                          // rg 0..3
    int row0  = __builtin_amdgcn_readfirstlane(wv << 4);
    int cbase = __builtin_amdgcn_readfirstlane(cg << 7);
    int p     = px0 + lane;
    bool okp  = p < P;
    int pc    = okp ? p : P - 1;

    const float* Xp = X + (size_t)cbase * P + pc;
    const float* Wp = wT + (size_t)cbase * 64 + row0;

    float acc[16];
#pragma unroll
    for (int r = 0; r < 16; ++r) acc[r] = 0.f;

    float xa[8], xb[8];
#pragma unroll
    for (int i = 0; i < 8; ++i) xa[i] = Xp[(size_t)i * P];

    for (int c0 = 0; c0 < 128; c0 += 8) {
        if (c0 + 8 < 128) {
#pragma unroll
            for (int i = 0; i < 8; ++i) xb[i] = Xp[(size_t)(c0 + 8 + i) * P];
        }
#pragma unroll
        for (int i = 0; i < 8; ++i) {
            const float* wr = Wp + (size_t)(c0 + i) * 64;
            float x = xa[i];
#pragma unroll
            for (int r4 = 0; r4 < 4; ++r4) {
                float4 wq = *(const float4*)(wr + r4 * 4);
                acc[r4*4+0] = fmaf(x, wq.x, acc[r4*4+0]);
                acc[r4*4+1] = fmaf(x, wq.y, acc[r4*4+1]);
                acc[r4*4+2] = fmaf(x, wq.z, acc[r4*4+2]);
                acc[r4*4+3] = fmaf(x, wq.w, acc[r4*4+3]);
            }
        }
#pragma unroll
        for (int i = 0; i < 8; ++i) xa[i] = xb[i];
    }

    if (okp) {
        float* op = Pout + (size_t)p * 64 + row0;
#pragma unroll
        for (int r4 = 0; r4 < 4; ++r4)
            *(float4*)(op + r4 * 4) = make_float4(acc[r4*4+0], acc[r4*4+1],
                                                  acc[r4*4+2], acc[r4*4+3]);
    }
}

// ---------------- head: reduce partials, bias+relu, feat2-up add, wo conv,
//                  softmax, argmax -> prb/seg in ws
__global__ __launch_bounds__(256) void head_kernel(const float* __restrict__ outp,
                                                   const float* __restrict__ wo,
                                                   const float* __restrict__ bo,
                                                   const float* __restrict__ b1v,
                                                   const float* __restrict__ b2v,
                                                   float* __restrict__ ws) {
    __shared__ float swo[NK * 64];
    __shared__ float sbo[NK];
    __shared__ float sb1[64], sb2[64];
    for (int i = threadIdx.x; i < NK * 64; i += 256) swo[i] = wo[i];
    if (threadIdx.x < NK) sbo[threadIdx.x] = bo[threadIdx.x];
    if (threadIdx.x < 64) { sb1[threadIdx.x] = b1v[threadIdx.x]; sb2[threadIdx.x] = b2v[threadIdx.x]; }
    __syncthreads();

    int p  = blockIdx.x * 256 + threadIdx.x;   // 0..19199
    int b  = p / P1;
    int pb = p % P1;
    int y  = pb / W1p, x = pb % W1p;
    int qg = b * P2 + (y >> 1) * W2p + (x >> 1);   // global quarter-pixel

    const float* c1g = outp + F1P_OFF + (size_t)p * 64;
    const float* f2g = outp + F2P_OFF + (size_t)qg * 64;
    const size_t CS = (size_t)NP1 * 64;   // stride between c1 groups
    const size_t FS = (size_t)NP2 * 64;   // stride between f2 groups

    float ok[NK];
#pragma unroll
    for (int k = 0; k < NK; ++k) ok[k] = sbo[k];
#pragma unroll
    for (int o4 = 0; o4 < 16; ++o4) {
        float4 a0 = *(const float4*)(c1g + 0*CS + o4*4);
        float4 a1 = *(const float4*)(c1g + 1*CS + o4*4);
        float4 a2 = *(const float4*)(c1g + 2*CS + o4*4);
        float4 a3 = *(const float4*)(c1g + 3*CS + o4*4);
        float4 g0 = *(const float4*)(f2g + 0*FS + o4*4);
        float4 g1 = *(const float4*)(f2g + 1*FS + o4*4);
        float4 g2 = *(const float4*)(f2g + 2*FS + o4*4);
        float4 g3 = *(const float4*)(f2g + 3*FS + o4*4);
        float co[4];
#pragma unroll
        for (int j = 0; j < 4; ++j) {
            int o = o4 * 4 + j;
            float s1 = ((const float*)&a0)[j] + ((const float*)&a1)[j]
                     + ((const float*)&a2)[j] + ((const float*)&a3)[j] + sb1[o];
            s1 = s1 > 0.f ? s1 : 0.f;
            float s2 = ((const float*)&g0)[j] + ((const float*)&g1)[j]
                     + ((const float*)&g2)[j] + ((const float*)&g3)[j] + sb2[o];
            s2 = s2 > 0.f ? s2 : 0.f;
            co[j] = s1 + s2;
        }
#pragma unroll
        for (int j = 0; j < 4; ++j) {
            int o = o4 * 4 + j;
#pragma unroll
            for (int k = 0; k < NK; ++k) ok[k] = fmaf(co[j], swo[k * 64 + o], ok[k]);
        }
    }
    float m = 0.f;
#pragma unroll
    for (int k = 0; k < NK; ++k) {
        ok[k] = ok[k] > 0.f ? ok[k] : 0.f;          // relu(out)
        if (ok[k] > m) m = ok[k];
    }
    float e[NK], sum = 0.f;
#pragma unroll
    for (int k = 0; k < NK; ++k) { e[k] = expf(ok[k] - m); sum += e[k]; }
    float inv = 1.f / sum;
    int arg = 0; float best = ok[0];
#pragma unroll
    for (int k = 1; k < NK; ++k) { if (ok[k] > best) { best = ok[k]; arg = k; } }

    float* pr = ws + WS_PRB + (size_t)p * 12;
#pragma unroll
    for (int k = 0; k < NK; ++k) pr[k] = e[k] * inv;
    pr[11] = (float)arg;
    ((int*)(ws + WS_SEG))[p] = arg;
}

// ---------------- upsample 8x: pure streaming replicate-store ----------------
__global__ __launch_bounds__(256) void upsample_kernel(const float* __restrict__ ws,
                                                       float* __restrict__ out) {
    const float* prb = ws + WS_PRB;
    unsigned total4 = (unsigned)((SEG_OFF + (size_t)NB * PLANE) / 4);  // 3,686,400
    unsigned step = gridDim.x * 256;
    for (unsigned i4 = blockIdx.x * 256 + threadIdx.x; i4 < total4; i4 += step) {
        unsigned f = i4 * 4;
        float v;
        if (f < (unsigned)SEG_OFF) {
            unsigned plane = f / (unsigned)PLANE;      // 0..43
            unsigned r = f - plane * (unsigned)PLANE;
            unsigned b = plane / NK, k = plane - b * NK;
            unsigned y = r / WOp, x = r - y * WOp;
            unsigned p = b * P1 + (y >> 3) * W1p + (x >> 3);
            v = prb[p * 12 + k];
        } else {
            unsigned g = f - (unsigned)SEG_OFF;
            unsigned b = g / (unsigned)PLANE;
            unsigned r = g - b * (unsigned)PLANE;
            unsigned y = r / WOp, x = r - y * WOp;
            unsigned p = b * P1 + (y >> 3) * W1p + (x >> 3);
            v = prb[p * 12 + 11];
        }
        *(float4*)(out + f) = make_float4(v, v, v, v);
    }
}

// ---------------- bbox: per-(batch,class) min/max/count over 60x80 seg ----------------
__global__ __launch_bounds__(256) void bbx_kernel(const float* __restrict__ ws,
                                                  float* __restrict__ out) {
    __shared__ int cnt[10], xmn[10], xmx[10], ymn[10], ymx[10];
    int b = blockIdx.x;
    int t = threadIdx.x;
    if (t < 10) { cnt[t] = 0; xmn[t] = 1 << 30; xmx[t] = -1; ymn[t] = 1 << 30; ymx[t] = -1; }
    __syncthreads();
    const int* seg = (const int*)(ws + WS_SEG) + b * P1;
    for (int p = t; p < P1; p += 256) {
        int s = seg[p];
        if (s >= 1 && s <= 9) {
            int y = p / W1p, x = p % W1p;
            atomicAdd(&cnt[s], 1);
            atomicMin(&xmn[s], x); atomicMax(&xmx[s], x);
            atomicMin(&ymn[s], y); atomicMax(&ymx[s], y);
        }
    }
    __syncthreads();
    if (t < 9) {
        int c = t + 1;
        bool valid = cnt[c] * 64 >= 500;    // upsampled count = 64*count
        float r[6];
        if (valid) {
            r[0] = (float)b;
            r[1] = (float)(xmn[c] * 8);
            r[2] = (float)(ymn[c] * 8);
            r[3] = (float)(xmx[c] * 8 + 7);
            r[4] = (float)(ymx[c] * 8 + 7);
            r[5] = (float)c;
        } else {
            for (int i = 0; i < 6; ++i) r[i] = -1.f;
        }
        float* row = out + BBX_OFF + (size_t)(b * 9 + t) * 6;
        for (int i = 0; i < 6; ++i) row[i] = r[i];
    }
}

extern "C" void kernel_launch(void* const* d_in, const int* in_sizes, int n_in,
                              void* d_out, int out_size, void* d_ws, size_t ws_size,
                              hipStream_t stream) {
    const float* f1 = (const float*)d_in[0];
    const float* f2 = (const float*)d_in[1];
    const float* w1 = (const float*)d_in[2];
    const float* b1 = (const float*)d_in[3];
    const float* w2 = (const float*)d_in[4];
    const float* b2 = (const float*)d_in[5];
    const float* wo = (const float*)d_in[6];
    const float* bo = (const float*)d_in[7];
    float* ws  = (float*)d_ws;
    float* out = (float*)d_out;

    transpose_w<<<128, 256, 0, stream>>>(w1, w2, ws);
    conv_part<<<1504, 256, 0, stream>>>(f1, f2, ws + WS_WT1, ws + WS_WT2, out);
    head_kernel<<<75, 256, 0, stream>>>(out, wo, bo, b1, b2, ws);
    upsample_kernel<<<2048, 256, 0, stream>>>(ws, out);
    bbx_kernel<<<NB, 256, 0, stream>>>(ws, out);
}

// Round 6
// 79.093 us; speedup vs baseline: 1.0699x; 1.0699x over previous
//
#include <hip/hip_runtime.h>
#include <math.h>

#define NB   4
#define CIN  512
#define HID  64
#define NK   11     // NUM_CLASSES+1
#define H1   60
#define W1p  80
#define P1   4800
#define H2   30
#define W2p  40
#define P2   1200
#define HO   480
#define WOp  640
#define NP1  (NB*P1)    // 19200
#define NP2  (NB*P2)    // 4800
#define PLANE ((size_t)HO*WOp)                  // 307200
#define SEG_OFF ((size_t)NB*NK*PLANE)           // 13,516,800
#define BBX_OFF (SEG_OFF + (size_t)NB*PLANE)    // 14,745,600

// partial-sum scratch inside d_out's probability region (fully overwritten by
// upsample_kernel afterwards): 2 K-halves of c1 partials + 2 of f2 partials.
#define F1P_OFF 0
#define F2P_OFF ((size_t)2 * NP1 * 64)          // 2,457,600 (total 3.07M < 13.5M)

// ws layout in floats
#define WS_WT1 0
#define WS_WT2 32768
#define WS_PRB 65536                            // 19200*12 = 230,400
#define WS_SEG (WS_PRB + NP1*12)                // 19200 ints

// ---------------- transpose weights: wT[c*64+o] = w[o*512+c] ----------------
__global__ __launch_bounds__(256) void transpose_w(const float* __restrict__ w1,
                                                   const float* __restrict__ w2,
                                                   float* __restrict__ ws) {
    int i = blockIdx.x * 256 + threadIdx.x;   // 0..32767
    if (i >= HID * CIN) return;
    int o = i >> 9;           // /512
    int c = i & 511;
    ws[WS_WT1 + c * HID + o] = w1[i];
    ws[WS_WT2 + c * HID + o] = w2[i];
}

// ---------------- conv partials, float4-pixel version --------------------
// 768 blocks x 256 thr. Block = (256-px tile) x (16-row group rg) x (K-half).
// Wave cg in block owns 64 channels; lane owns 4 consecutive pixels (float4
// x-loads: 1KB/wave/op, 4x fewer VMEM ops than dword version). acc[16][4].
// 8-ch double-buffer prefetch: one chunk = 512 FMA instr = 1024cy coverage.
// LDS reduce 4 waves -> wave 0 stores partial[half][px][64] to d_out scratch.
// 48KB LDS -> 3 blocks/CU, all 768 blocks resident (3 waves/SIMD).
__global__ __launch_bounds__(256) void conv_part(const float* __restrict__ f1,
                                                 const float* __restrict__ f2,
                                                 const float* __restrict__ wt1,
                                                 const float* __restrict__ wt2,
                                                 float* __restrict__ outp) {
    __shared__ float red[3][16][256];   // [cg-1][row][px-in-tile]
    int t = blockIdx.x;
    const float* X; const float* wT; float* Pout;
    int P, px0, sub;
    if (t < 608) {                       // f1: 4 batches x 19 tiles x 8 (rg,half)
        int tile = t >> 3; sub = t & 7;
        int b = tile / 19; px0 = (tile % 19) * 256;
        X  = f1 + (size_t)b * CIN * P1;  P = P1;
        wT = wt1;
        Pout = outp + F1P_OFF + (size_t)(sub & 1) * NP1 * 64 + (size_t)b * P1 * 64;
    } else {                             // f2: 4 batches x 5 tiles x 8
        int u = t - 608;
        int tile = u >> 3; sub = u & 7;
        int b = tile / 5;  px0 = (tile % 5) * 256;
        X  = f2 + (size_t)b * CIN * P2;  P = P2;
        wT = wt2;
        Pout = outp + F2P_OFF + (size_t)(sub & 1) * NP2 * 64 + (size_t)b * P2 * 64;
    }
    int lane  = threadIdx.x & 63;
    int cg    = threadIdx.x >> 6;                              // 0..3
    int row0  = (sub >> 1) << 4;                               // rg*16 (SGPR)
    int cbase = __builtin_amdgcn_readfirstlane(((sub & 1) << 8) + (cg << 6));
    int pxl   = px0 + lane * 4;
    bool okp  = pxl < P;                 // P%4==0 -> whole float4 in range
    int pxc   = okp ? pxl : P - 4;

    const float* Xp = X + (size_t)cbase * P + pxc;
    const float* Wp = wT + (size_t)cbase * 64 + row0;

    float acc[16][4];
#pragma unroll
    for (int r = 0; r < 16; ++r)
#pragma unroll
        for (int q = 0; q < 4; ++q) acc[r][q] = 0.f;

    float4 xa[8], xb[8];
#pragma unroll
    for (int i = 0; i < 8; ++i) xa[i] = *(const float4*)(Xp + (size_t)i * P);
    const float* xload = Xp + (size_t)8 * P;
    const float* wptr  = Wp;

    for (int c0 = 0; c0 < 64; c0 += 8) {
        if (c0 < 56) {
#pragma unroll
            for (int i = 0; i < 8; ++i) xb[i] = *(const float4*)(xload + (size_t)i * P);
            xload += (size_t)8 * P;
        }
#pragma unroll
        for (int i = 0; i < 8; ++i) {
            const float* wr = wptr + i * 64;
            float4 x = xa[i];
#pragma unroll
            for (int r = 0; r < 16; ++r) {
                float w = wr[r];
                acc[r][0] = fmaf(x.x, w, acc[r][0]);
                acc[r][1] = fmaf(x.y, w, acc[r][1]);
                acc[r][2] = fmaf(x.z, w, acc[r][2]);
                acc[r][3] = fmaf(x.w, w, acc[r][3]);
            }
        }
        wptr += 8 * 64;
#pragma unroll
        for (int i = 0; i < 8; ++i) xa[i] = xb[i];
    }

    if (cg > 0) {
#pragma unroll
        for (int r = 0; r < 16; ++r)
            *(float4*)&red[cg - 1][r][lane * 4] =
                make_float4(acc[r][0], acc[r][1], acc[r][2], acc[r][3]);
    }
    __syncthreads();
    if (cg == 0 && okp) {
#pragma unroll
        for (int r = 0; r < 16; ++r) {
            float4 s0 = *(float4*)&red[0][r][lane * 4];
            float4 s1 = *(float4*)&red[1][r][lane * 4];
            float4 s2 = *(float4*)&red[2][r][lane * 4];
            acc[r][0] += s0.x + s1.x + s2.x;
            acc[r][1] += s0.y + s1.y + s2.y;
            acc[r][2] += s0.z + s1.z + s2.z;
            acc[r][3] += s0.w + s1.w + s2.w;
        }
        float* op = Pout + (size_t)pxl * 64 + row0;
#pragma unroll
        for (int q = 0; q < 4; ++q) {
#pragma unroll
            for (int r4 = 0; r4 < 4; ++r4) {
                *(float4*)(op + q * 64 + r4 * 4) =
                    make_float4(acc[r4*4+0][q], acc[r4*4+1][q],
                                acc[r4*4+2][q], acc[r4*4+3][q]);
            }
        }
    }
}

// ---------------- head: reduce 2 K-halves, bias+relu, feat2-up add, wo conv,
//                  softmax, argmax -> prb/seg in ws
__global__ __launch_bounds__(256) void head_kernel(const float* __restrict__ outp,
                                                   const float* __restrict__ wo,
                                                   const float* __restrict__ bo,
                                                   const float* __restrict__ b1v,
                                                   const float* __restrict__ b2v,
                                                   float* __restrict__ ws) {
    __shared__ float swo[NK * 64];
    __shared__ float sbo[NK];
    __shared__ float sb1[64], sb2[64];
    for (int i = threadIdx.x; i < NK * 64; i += 256) swo[i] = wo[i];
    if (threadIdx.x < NK) sbo[threadIdx.x] = bo[threadIdx.x];
    if (threadIdx.x < 64) { sb1[threadIdx.x] = b1v[threadIdx.x]; sb2[threadIdx.x] = b2v[threadIdx.x]; }
    __syncthreads();

    int p  = blockIdx.x * 256 + threadIdx.x;   // 0..19199
    int b  = p / P1;
    int pb = p % P1;
    int y  = pb / W1p, x = pb % W1p;
    int qg = b * P2 + (y >> 1) * W2p + (x >> 1);   // global quarter-pixel

    const float* c1g = outp + F1P_OFF + (size_t)p * 64;
    const float* f2g = outp + F2P_OFF + (size_t)qg * 64;
    const size_t CS = (size_t)NP1 * 64;   // stride between c1 halves
    const size_t FS = (size_t)NP2 * 64;   // stride between f2 halves

    float ok[NK];
#pragma unroll
    for (int k = 0; k < NK; ++k) ok[k] = sbo[k];
#pragma unroll
    for (int o4 = 0; o4 < 16; ++o4) {
        float4 a0 = *(const float4*)(c1g + 0*CS + o4*4);
        float4 a1 = *(const float4*)(c1g + 1*CS + o4*4);
        float4 g0 = *(const float4*)(f2g + 0*FS + o4*4);
        float4 g1 = *(const float4*)(f2g + 1*FS + o4*4);
        float co[4];
#pragma unroll
        for (int j = 0; j < 4; ++j) {
            int o = o4 * 4 + j;
            float s1 = ((const float*)&a0)[j] + ((const float*)&a1)[j] + sb1[o];
            s1 = s1 > 0.f ? s1 : 0.f;
            float s2 = ((const float*)&g0)[j] + ((const float*)&g1)[j] + sb2[o];
            s2 = s2 > 0.f ? s2 : 0.f;
            co[j] = s1 + s2;
        }
#pragma unroll
        for (int j = 0; j < 4; ++j) {
            int o = o4 * 4 + j;
#pragma unroll
            for (int k = 0; k < NK; ++k) ok[k] = fmaf(co[j], swo[k * 64 + o], ok[k]);
        }
    }
    float m = 0.f;
#pragma unroll
    for (int k = 0; k < NK; ++k) {
        ok[k] = ok[k] > 0.f ? ok[k] : 0.f;          // relu(out)
        if (ok[k] > m) m = ok[k];
    }
    float e[NK], sum = 0.f;
#pragma unroll
    for (int k = 0; k < NK; ++k) { e[k] = expf(ok[k] - m); sum += e[k]; }
    float inv = 1.f / sum;
    int arg = 0; float best = ok[0];
#pragma unroll
    for (int k = 1; k < NK; ++k) { if (ok[k] > best) { best = ok[k]; arg = k; } }

    float* pr = ws + WS_PRB + (size_t)p * 12;
#pragma unroll
    for (int k = 0; k < NK; ++k) pr[k] = e[k] * inv;
    pr[11] = (float)arg;
    ((int*)(ws + WS_SEG))[p] = arg;
}

// ---------------- upsample 8x: pure streaming replicate-store ----------------
__global__ __launch_bounds__(256) void upsample_kernel(const float* __restrict__ ws,
                                                       float* __restrict__ out) {
    const float* prb = ws + WS_PRB;
    unsigned total4 = (unsigned)((SEG_OFF + (size_t)NB * PLANE) / 4);  // 3,686,400
    unsigned step = gridDim.x * 256;
    for (unsigned i4 = blockIdx.x * 256 + threadIdx.x; i4 < total4; i4 += step) {
        unsigned f = i4 * 4;
        float v;
        if (f < (unsigned)SEG_OFF) {
            unsigned plane = f / (unsigned)PLANE;      // 0..43
            unsigned r = f - plane * (unsigned)PLANE;
            unsigned b = plane / NK, k = plane - b * NK;
            unsigned y = r / WOp, x = r - y * WOp;
            unsigned p = b * P1 + (y >> 3) * W1p + (x >> 3);
            v = prb[p * 12 + k];
        } else {
            unsigned g = f - (unsigned)SEG_OFF;
            unsigned b = g / (unsigned)PLANE;
            unsigned r = g - b * (unsigned)PLANE;
            unsigned y = r / WOp, x = r - y * WOp;
            unsigned p = b * P1 + (y >> 3) * W1p + (x >> 3);
            v = prb[p * 12 + 11];
        }
        *(float4*)(out + f) = make_float4(v, v, v, v);
    }
}

// ---------------- bbox: per-(batch,class) min/max/count over 60x80 seg ----------------
__global__ __launch_bounds__(256) void bbx_kernel(const float* __restrict__ ws,
                                                  float* __restrict__ out) {
    __shared__ int cnt[10], xmn[10], xmx[10], ymn[10], ymx[10];
    int b = blockIdx.x;
    int t = threadIdx.x;
    if (t < 10) { cnt[t] = 0; xmn[t] = 1 << 30; xmx[t] = -1; ymn[t] = 1 << 30; ymx[t] = -1; }
    __syncthreads();
    const int* seg = (const int*)(ws + WS_SEG) + b * P1;
    for (int p = t; p < P1; p += 256) {
        int s = seg[p];
        if (s >= 1 && s <= 9) {
            int y = p / W1p, x = p % W1p;
            atomicAdd(&cnt[s], 1);
            atomicMin(&xmn[s], x); atomicMax(&xmx[s], x);
            atomicMin(&ymn[s], y); atomicMax(&ymx[s], y);
        }
    }
    __syncthreads();
    if (t < 9) {
        int c = t + 1;
        bool valid = cnt[c] * 64 >= 500;    // upsampled count = 64*count
        float r[6];
        if (valid) {
            r[0] = (float)b;
            r[1] = (float)(xmn[c] * 8);
            r[2] = (float)(ymn[c] * 8);
            r[3] = (float)(xmx[c] * 8 + 7);
            r[4] = (float)(ymx[c] * 8 + 7);
            r[5] = (float)c;
        } else {
            for (int i = 0; i < 6; ++i) r[i] = -1.f;
        }
        float* row = out + BBX_OFF + (size_t)(b * 9 + t) * 6;
        for (int i = 0; i < 6; ++i) row[i] = r[i];
    }
}

extern "C" void kernel_launch(void* const* d_in, const int* in_sizes, int n_in,
                              void* d_out, int out_size, void* d_ws, size_t ws_size,
                              hipStream_t stream) {
    const float* f1 = (const float*)d_in[0];
    const float* f2 = (const float*)d_in[1];
    const float* w1 = (const float*)d_in[2];
    const float* b1 = (const float*)d_in[3];
    const float* w2 = (const float*)d_in[4];
    const float* b2 = (const float*)d_in[5];
    const float* wo = (const float*)d_in[6];
    const float* bo = (const float*)d_in[7];
    float* ws  = (float*)d_ws;
    float* out = (float*)d_out;

    transpose_w<<<128, 256, 0, stream>>>(w1, w2, ws);
    conv_part<<<768, 256, 0, stream>>>(f1, f2, ws + WS_WT1, ws + WS_WT2, out);
    head_kernel<<<75, 256, 0, stream>>>(out, wo, bo, b1, b2, ws);
    upsample_kernel<<<2048, 256, 0, stream>>>(ws, out);
    bbx_kernel<<<NB, 256, 0, stream>>>(ws, out);
}